// Round 10
// baseline (414.805 us; speedup 1.0000x reference)
//
#include <hip/hip_runtime.h>
#include <math.h>

#define N_   8
#define C_   64
#define H_   128
#define W_   128
#define HW_  (H_ * W_)
#define CHW_ (C_ * HW_)
#define K_   3
#define CI_TILE 8
#define CO_BLK  16
#define N_CG    (C_ / CO_BLK)   // 4 co-groups
#define TILE_H 32               // 2x2 pixels per thread: 16x16 threads -> 32x32 tile
#define TILE_W 32
#define HALO_H (TILE_H + 2)      // 34
#define HALO_W (TILE_W + 2)      // 34
#define XSTR   36                // even stride (b64-aligned rows)
#define CISZ   (HALO_H * XSTR)   // 1224 floats per ci plane
#define PLANE  (HALO_H * HALO_W) // 1156 staged elems per ci plane
#define NSLOT  5                 // ceil(1156/256)
#define WROW 12                  // padded weight row (9 used) -> 16B-aligned
#define WCI  (CO_BLK * WROW)     // 192 floats per ci
#define WSTRIDE (C_ * K_ * K_)   // 576 floats between consecutive co's
#define BN_EPS 1e-5
#define POW_EPS 1e-12f

// One |x-w| accumulate in EXACTLY 2 VALU instructions (VGPR operands).
#define MAC_TERM(accv, wv, xvk) do { float t_;                         \
    asm("v_sub_f32 %1, %2, %3\n\t"                                     \
        "v_add_f32 %0, %0, |%1|"                                       \
        : "+v"(accv), "=&v"(t_)                                        \
        : "v"(wv), "v"(xvk));                                          \
  } while (0)

// R9 post-mortem: VMEM weight path thrashed L1 (multiple blocks/CU x 18KB
// windows) -> reverted to R8's LDS-weight base. R8 was stall-bound (deflated
// VALUBusy ~53% @43% occ): each co's 36-MAC burst waits on 3 lgkm reads.
// This version: 2x2 pixels/thread. Per wave-ci VALU doubles (1152->2304 cyc)
// while LDS fetches grow by only 2 ds_read_b64 -> each weight read feeds
// 144 VALU cyc (vs 72), covering LDS latency in-wave. Trades occupancy
// (2 blocks/CU) for per-wave ILP, which R8 showed is the binding constraint.
__global__ __launch_bounds__(256, 2) void adder_kernel(
    const float* __restrict__ x, const float* __restrict__ weight,
    float* __restrict__ y, double* __restrict__ sums)
{
    __shared__ __align__(16) float sx[CI_TILE * CISZ];   // 39168 B
    __shared__ __align__(16) float wl[CI_TILE * WCI];    //  6144 B
    __shared__ float red[CO_BLK][2][4];                  // stat partials

    const int tx = threadIdx.x & 15;        // col-pair 0..15 (2 cols each)
    const int ty = threadIdx.x >> 4;        // row-pair 0..15 (2 rows each)
    const int tile_h = blockIdx.x >> 2;     // 4 tiles of 32 rows
    const int tile_w = blockIdx.x & 3;      // 4 tiles of 32 cols
    const int n   = blockIdx.y;
    const int co0 = blockIdx.z * CO_BLK;
    const int h0 = tile_h * TILE_H;
    const int w0 = tile_w * TILE_W;

    float a00[CO_BLK], a01[CO_BLK], a10[CO_BLK], a11[CO_BLK];
#pragma unroll
    for (int j = 0; j < CO_BLK; ++j) { a00[j]=0.f; a01[j]=0.f; a10[j]=0.f; a11[j]=0.f; }

    const float* xn = x + n * CHW_;

    // ---- One-time affine staging offsets (5 slots cover the 1156-elem plane).
    int lx[NSLOT], gx[NSLOT];
#pragma unroll
    for (int s = 0; s < NSLOT; ++s) {
        int idx = threadIdx.x + s * 256;
        if (idx < PLANE) {
            int r = idx / HALO_W, c = idx - r * HALO_W;
            int gh = h0 + r - 1, gw = w0 + c - 1;
            lx[s] = r * XSTR + c;
            gx[s] = ((unsigned)gh < (unsigned)H_ && (unsigned)gw < (unsigned)W_)
                    ? (gh * W_ + gw) : -1;
        } else { lx[s] = -1; gx[s] = -1; }
    }
    // weight slice: threads 0..143 each own one (co,k); ci loop affine.
    int wlo = -1, wgo = 0;
    if (threadIdx.x < CO_BLK * 9) {
        int co = threadIdx.x / 9, k = threadIdx.x - co * 9;
        wlo = co * WROW + k;
        wgo = (co0 + co) * WSTRIDE + k;
    }

    for (int cb = 0; cb < C_; cb += CI_TILE) {
        const float* xncb = xn + cb * HW_;
        __syncthreads();  // previous chunk fully read before overwrite
#pragma unroll
        for (int ci = 0; ci < CI_TILE; ++ci) {
#pragma unroll
            for (int s = 0; s < NSLOT; ++s) {
                if (lx[s] >= 0) {
                    float v = (gx[s] >= 0) ? xncb[ci * HW_ + gx[s]] : 0.f;
                    sx[ci * CISZ + lx[s]] = v;
                }
            }
        }
        if (wlo >= 0) {
            const float* wgp = weight + wgo + cb * 9;
#pragma unroll
            for (int ci = 0; ci < CI_TILE; ++ci)
                wl[ci * WCI + wlo] = wgp[ci * 9];
        }
        __syncthreads();

#pragma unroll 1
        for (int ci = 0; ci < CI_TILE; ++ci) {
            const float* sxc = &sx[ci * CISZ];
            // 4x4 window serves the 2x2 pixel quad: 8x ds_read_b64.
            float xv[4][4];
#pragma unroll
            for (int r = 0; r < 4; ++r) {
                float2 a = *(const float2*)(sxc + (2 * ty + r) * XSTR + 2 * tx);
                float2 b = *(const float2*)(sxc + (2 * ty + r) * XSTR + 2 * tx + 2);
                xv[r][0] = a.x; xv[r][1] = a.y; xv[r][2] = b.x; xv[r][3] = b.y;
            }

            const float* wrow = &wl[ci * WCI];
#pragma unroll
            for (int j = 0; j < CO_BLK; ++j) {
                float4 wa = *(const float4*)(wrow + j * WROW);
                float4 wb = *(const float4*)(wrow + j * WROW + 4);
                float  w8 = wrow[j * WROW + 8];
                // tap (kh,kw) feeds pixel (pr,pc) from xv[pr+kh][pc+kw]
                MAC_TERM(a00[j], wa.x, xv[0][0]); MAC_TERM(a01[j], wa.x, xv[0][1]);
                MAC_TERM(a10[j], wa.x, xv[1][0]); MAC_TERM(a11[j], wa.x, xv[1][1]);
                MAC_TERM(a00[j], wa.y, xv[0][1]); MAC_TERM(a01[j], wa.y, xv[0][2]);
                MAC_TERM(a10[j], wa.y, xv[1][1]); MAC_TERM(a11[j], wa.y, xv[1][2]);
                MAC_TERM(a00[j], wa.z, xv[0][2]); MAC_TERM(a01[j], wa.z, xv[0][3]);
                MAC_TERM(a10[j], wa.z, xv[1][2]); MAC_TERM(a11[j], wa.z, xv[1][3]);
                MAC_TERM(a00[j], wa.w, xv[1][0]); MAC_TERM(a01[j], wa.w, xv[1][1]);
                MAC_TERM(a10[j], wa.w, xv[2][0]); MAC_TERM(a11[j], wa.w, xv[2][1]);
                MAC_TERM(a00[j], wb.x, xv[1][1]); MAC_TERM(a01[j], wb.x, xv[1][2]);
                MAC_TERM(a10[j], wb.x, xv[2][1]); MAC_TERM(a11[j], wb.x, xv[2][2]);
                MAC_TERM(a00[j], wb.y, xv[1][2]); MAC_TERM(a01[j], wb.y, xv[1][3]);
                MAC_TERM(a10[j], wb.y, xv[2][2]); MAC_TERM(a11[j], wb.y, xv[2][3]);
                MAC_TERM(a00[j], wb.z, xv[2][0]); MAC_TERM(a01[j], wb.z, xv[2][1]);
                MAC_TERM(a10[j], wb.z, xv[3][0]); MAC_TERM(a11[j], wb.z, xv[3][1]);
                MAC_TERM(a00[j], wb.w, xv[2][1]); MAC_TERM(a01[j], wb.w, xv[2][2]);
                MAC_TERM(a10[j], wb.w, xv[3][1]); MAC_TERM(a11[j], wb.w, xv[3][2]);
                MAC_TERM(a00[j], w8,   xv[2][2]); MAC_TERM(a01[j], w8,   xv[2][3]);
                MAC_TERM(a10[j], w8,   xv[3][2]); MAC_TERM(a11[j], w8,   xv[3][3]);
            }
        }
    }

    // Epilogue: y = -acc + residual (2 rows x float2); fused sum/sumsq.
    const int r0 = h0 + 2 * ty, c0 = w0 + 2 * tx;
    float* yo = y + n * CHW_ + co0 * HW_ + r0 * W_ + c0;
    const float* xrp = xn + co0 * HW_ + r0 * W_ + c0;
    const int lane = threadIdx.x & 63;
    const int wid  = threadIdx.x >> 6;

#pragma unroll
    for (int j = 0; j < CO_BLK; ++j) {
        float2 rv0 = *(const float2*)(xrp + j * HW_);
        float2 rv1 = *(const float2*)(xrp + j * HW_ + W_);
        float v00 = -a00[j] + rv0.x, v01 = -a01[j] + rv0.y;
        float v10 = -a10[j] + rv1.x, v11 = -a11[j] + rv1.y;
        float2 o0; o0.x = v00; o0.y = v01;
        float2 o1; o1.x = v10; o1.y = v11;
        *(float2*)(yo + j * HW_)      = o0;
        *(float2*)(yo + j * HW_ + W_) = o1;
        float s  = v00 + v01 + v10 + v11;
        float ss = v00 * v00 + v01 * v01 + v10 * v10 + v11 * v11;
#pragma unroll
        for (int off = 32; off > 0; off >>= 1) {
            s  += __shfl_down(s, off);
            ss += __shfl_down(ss, off);
        }
        if (lane == 0) { red[j][0][wid] = s; red[j][1][wid] = ss; }
    }
    __syncthreads();
    if (threadIdx.x < CO_BLK) {
        int j = threadIdx.x;
        float S  = red[j][0][0] + red[j][0][1] + red[j][0][2] + red[j][0][3];
        float SS = red[j][1][0] + red[j][1][1] + red[j][1][2] + red[j][1][3];
        atomicAdd(&sums[co0 + j], (double)S);
        atomicAdd(&sums[C_ + co0 + j], (double)SS);
    }
}

// Per-channel scale/shift from batch stats.
__global__ void finalize_kernel(const double* __restrict__ sums,
                                const float* __restrict__ gamma,
                                const float* __restrict__ beta,
                                float* __restrict__ sc)
{
    const int c = threadIdx.x;  // 64 threads
    const double cnt = (double)(N_ * HW_);
    double mean = sums[c] / cnt;
    double var  = sums[C_ + c] / cnt - mean * mean;
    float inv   = (float)(1.0 / sqrt(var + (double)BN_EPS));
    float scale = gamma[c] * inv;
    float shift = beta[c] - (float)mean * scale;
    sc[c]      = scale;
    sc[C_ + c] = shift;
}

// In-place BN affine + power activation, float4 vectorized.
// alpha==1 fast path: sign(t)*(|t|+1e-12)^1 = t +- 1e-12 (below tolerance).
__global__ __launch_bounds__(256) void apply_kernel(
    float* __restrict__ y, const float* __restrict__ sc,
    const float* __restrict__ alpha_p)
{
    const int idx = blockIdx.x * 256 + threadIdx.x;   // float4 index
    const float alpha = alpha_p[0];
    const int e0 = idx * 4;
    const int c = (e0 / HW_) & (C_ - 1);   // HW_ divisible by 4: all 4 in same channel
    const float scale = sc[c];
    const float shift = sc[C_ + c];

    float4 v = reinterpret_cast<float4*>(y)[idx];
    float* pv = reinterpret_cast<float*>(&v);
    if (alpha == 1.0f) {
#pragma unroll
        for (int i = 0; i < 4; ++i)
            pv[i] = pv[i] * scale + shift;
    } else {
#pragma unroll
        for (int i = 0; i < 4; ++i) {
            float t = pv[i] * scale + shift;
            float sgn = (t > 0.f) ? 1.f : ((t < 0.f) ? -1.f : 0.f);
            pv[i] = sgn * powf(fabsf(t) + POW_EPS, alpha);
        }
    }
    reinterpret_cast<float4*>(y)[idx] = v;
}

extern "C" void kernel_launch(void* const* d_in, const int* in_sizes, int n_in,
                              void* d_out, int out_size, void* d_ws, size_t ws_size,
                              hipStream_t stream)
{
    const float* x      = (const float*)d_in[0];
    const float* weight = (const float*)d_in[1];
    const float* gamma  = (const float*)d_in[2];
    const float* beta   = (const float*)d_in[3];
    const float* alpha  = (const float*)d_in[4];
    float* out = (float*)d_out;

    double* sums = (double*)d_ws;                                // 128 doubles
    float*  sc   = (float*)((char*)d_ws + 128 * sizeof(double)); // 128 floats

    hipMemsetAsync(d_ws, 0, 128 * sizeof(double), stream);

    adder_kernel<<<dim3(16, N_, N_CG), 256, 0, stream>>>(x, weight, out, sums);
    finalize_kernel<<<1, C_, 0, stream>>>(sums, gamma, beta, sc);

    const int n4 = (N_ * CHW_) / 4;           // 2,097,152 float4s
    apply_kernel<<<n4 / 256, 256, 0, stream>>>(out, sc, alpha);
}

// Round 11
// 301.393 us; speedup vs baseline: 1.3763x; 1.3763x over previous
//
#include <hip/hip_runtime.h>
#include <math.h>

#define N_   8
#define C_   64
#define H_   128
#define W_   128
#define HW_  (H_ * W_)
#define CHW_ (C_ * HW_)
#define K_   3
#define CI_TILE 4
#define CO_BLK  8
#define N_CG    (C_ / CO_BLK)   // 8 co-groups
#define TILE_H 16               // 8 row-threads x 2 px
#define TILE_W 32               // 16 col-threads x 2 px
#define HALO_H (TILE_H + 2)      // 18
#define HALO_W (TILE_W + 2)      // 34
#define XSTR   36                // b64-aligned row stride
#define CISZ   (HALO_H * XSTR)   // 648 floats per ci plane
#define PLANE  (HALO_H * HALO_W) // 612 staged elems per ci plane
#define NSLOT  5                 // ceil(612/128)
#define WROW 12                  // padded weight row (9 used) -> 16B-aligned
#define WCI  (CO_BLK * WROW)     // 96 floats per ci
#define WSTRIDE (C_ * K_ * K_)   // 576 floats between consecutive co's
#define BN_EPS 1e-5
#define POW_EPS 1e-12f

// One |x-w| accumulate in EXACTLY 2 VALU instructions (VGPR operands).
#define MAC_TERM(accv, wv, xvk) do { float t_;                         \
    asm("v_sub_f32 %1, %2, %3\n\t"                                     \
        "v_add_f32 %0, %0, |%1|"                                       \
        : "+v"(accv), "=&v"(t_)                                        \
        : "v"(wv), "v"(xvk));                                          \
  } while (0)

// R10 post-mortem: 4 px/thread was pipe-balanced but 2 blocks/CU starved
// (24% occ, steady state never reached during staging barriers). This keeps
// the 2x2 px/thread ILP but restores 8 independent blocks/CU with
// 128-thread blocks (CO_BLK=8, 16x32 tile, CI_TILE=4 -> 12 KB LDS).
// Pipe model @16 waves/CU: LDS ~4992 vs VALU ~4608 cyc/CU-ci -> balanced,
// and 8 barrier groups let staging overlap other blocks' MACs.
__global__ __launch_bounds__(128, 4) void adder_kernel(
    const float* __restrict__ x, const float* __restrict__ weight,
    float* __restrict__ y, double* __restrict__ sums)
{
    __shared__ __align__(16) float sx[CI_TILE * CISZ];   // 10368 B
    __shared__ __align__(16) float wl[CI_TILE * WCI];    //  1536 B
    __shared__ float red[CO_BLK][2][2];                  // stat partials

    const int tx = threadIdx.x & 15;        // col-pair 0..15
    const int ty = threadIdx.x >> 4;        // row-pair 0..7
    const int tile_h = blockIdx.x >> 2;     // 8 tiles of 16 rows
    const int tile_w = blockIdx.x & 3;      // 4 tiles of 32 cols
    const int n   = blockIdx.y;
    const int co0 = blockIdx.z * CO_BLK;
    const int h0 = tile_h * TILE_H;
    const int w0 = tile_w * TILE_W;

    float a00[CO_BLK], a01[CO_BLK], a10[CO_BLK], a11[CO_BLK];
#pragma unroll
    for (int j = 0; j < CO_BLK; ++j) { a00[j]=0.f; a01[j]=0.f; a10[j]=0.f; a11[j]=0.f; }

    const float* xn = x + n * CHW_;

    // One-time affine staging offsets (5 slots x 128 threads cover 612 elems).
    int lx[NSLOT], gx[NSLOT];
#pragma unroll
    for (int s = 0; s < NSLOT; ++s) {
        int idx = threadIdx.x + s * 128;
        if (idx < PLANE) {
            int r = idx / HALO_W, c = idx - r * HALO_W;
            int gh = h0 + r - 1, gw = w0 + c - 1;
            lx[s] = r * XSTR + c;
            gx[s] = ((unsigned)gh < (unsigned)H_ && (unsigned)gw < (unsigned)W_)
                    ? (gh * W_ + gw) : -1;
        } else { lx[s] = -1; gx[s] = -1; }
    }
    // weight slice: threads 0..71 each own one (co,k); ci loop affine.
    int wlo = -1, wgo = 0;
    if (threadIdx.x < CO_BLK * 9) {
        int co = threadIdx.x / 9, k = threadIdx.x - co * 9;
        wlo = co * WROW + k;
        wgo = (co0 + co) * WSTRIDE + k;
    }

    for (int cb = 0; cb < C_; cb += CI_TILE) {
        const float* xncb = xn + cb * HW_;
        __syncthreads();  // previous chunk fully read before overwrite
#pragma unroll
        for (int ci = 0; ci < CI_TILE; ++ci) {
#pragma unroll
            for (int s = 0; s < NSLOT; ++s) {
                if (lx[s] >= 0) {
                    float v = (gx[s] >= 0) ? xncb[ci * HW_ + gx[s]] : 0.f;
                    sx[ci * CISZ + lx[s]] = v;
                }
            }
        }
        if (wlo >= 0) {
            const float* wgp = weight + wgo + cb * 9;
#pragma unroll
            for (int ci = 0; ci < CI_TILE; ++ci)
                wl[ci * WCI + wlo] = wgp[ci * 9];
        }
        __syncthreads();

#pragma unroll 1
        for (int ci = 0; ci < CI_TILE; ++ci) {
            const float* sxc = &sx[ci * CISZ];
            // 4x4 window serves the 2x2 pixel quad: 8x ds_read_b64.
            float xv[4][4];
#pragma unroll
            for (int r = 0; r < 4; ++r) {
                float2 a = *(const float2*)(sxc + (2 * ty + r) * XSTR + 2 * tx);
                float2 b = *(const float2*)(sxc + (2 * ty + r) * XSTR + 2 * tx + 2);
                xv[r][0] = a.x; xv[r][1] = a.y; xv[r][2] = b.x; xv[r][3] = b.y;
            }

            const float* wrow = &wl[ci * WCI];
#pragma unroll
            for (int j = 0; j < CO_BLK; ++j) {
                float4 wa = *(const float4*)(wrow + j * WROW);
                float4 wb = *(const float4*)(wrow + j * WROW + 4);
                float  w8 = wrow[j * WROW + 8];
                // tap (kh,kw) feeds pixel (pr,pc) from xv[pr+kh][pc+kw]
                MAC_TERM(a00[j], wa.x, xv[0][0]); MAC_TERM(a01[j], wa.x, xv[0][1]);
                MAC_TERM(a10[j], wa.x, xv[1][0]); MAC_TERM(a11[j], wa.x, xv[1][1]);
                MAC_TERM(a00[j], wa.y, xv[0][1]); MAC_TERM(a01[j], wa.y, xv[0][2]);
                MAC_TERM(a10[j], wa.y, xv[1][1]); MAC_TERM(a11[j], wa.y, xv[1][2]);
                MAC_TERM(a00[j], wa.z, xv[0][2]); MAC_TERM(a01[j], wa.z, xv[0][3]);
                MAC_TERM(a10[j], wa.z, xv[1][2]); MAC_TERM(a11[j], wa.z, xv[1][3]);
                MAC_TERM(a00[j], wa.w, xv[1][0]); MAC_TERM(a01[j], wa.w, xv[1][1]);
                MAC_TERM(a10[j], wa.w, xv[2][0]); MAC_TERM(a11[j], wa.w, xv[2][1]);
                MAC_TERM(a00[j], wb.x, xv[1][1]); MAC_TERM(a01[j], wb.x, xv[1][2]);
                MAC_TERM(a10[j], wb.x, xv[2][1]); MAC_TERM(a11[j], wb.x, xv[2][2]);
                MAC_TERM(a00[j], wb.y, xv[1][2]); MAC_TERM(a01[j], wb.y, xv[1][3]);
                MAC_TERM(a10[j], wb.y, xv[2][2]); MAC_TERM(a11[j], wb.y, xv[2][3]);
                MAC_TERM(a00[j], wb.z, xv[2][0]); MAC_TERM(a01[j], wb.z, xv[2][1]);
                MAC_TERM(a10[j], wb.z, xv[3][0]); MAC_TERM(a11[j], wb.z, xv[3][1]);
                MAC_TERM(a00[j], wb.w, xv[2][1]); MAC_TERM(a01[j], wb.w, xv[2][2]);
                MAC_TERM(a10[j], wb.w, xv[3][1]); MAC_TERM(a11[j], wb.w, xv[3][2]);
                MAC_TERM(a00[j], w8,   xv[2][2]); MAC_TERM(a01[j], w8,   xv[2][3]);
                MAC_TERM(a10[j], w8,   xv[3][2]); MAC_TERM(a11[j], w8,   xv[3][3]);
            }
        }
    }

    // Epilogue: y = -acc + residual (2 rows x float2); fused sum/sumsq.
    const int r0 = h0 + 2 * ty, c0 = w0 + 2 * tx;
    float* yo = y + n * CHW_ + co0 * HW_ + r0 * W_ + c0;
    const float* xrp = xn + co0 * HW_ + r0 * W_ + c0;
    const int lane = threadIdx.x & 63;
    const int wid  = threadIdx.x >> 6;   // 0..1 (2 waves)

#pragma unroll
    for (int j = 0; j < CO_BLK; ++j) {
        float2 rv0 = *(const float2*)(xrp + j * HW_);
        float2 rv1 = *(const float2*)(xrp + j * HW_ + W_);
        float v00 = -a00[j] + rv0.x, v01 = -a01[j] + rv0.y;
        float v10 = -a10[j] + rv1.x, v11 = -a11[j] + rv1.y;
        float2 o0; o0.x = v00; o0.y = v01;
        float2 o1; o1.x = v10; o1.y = v11;
        *(float2*)(yo + j * HW_)      = o0;
        *(float2*)(yo + j * HW_ + W_) = o1;
        float s  = v00 + v01 + v10 + v11;
        float ss = v00 * v00 + v01 * v01 + v10 * v10 + v11 * v11;
#pragma unroll
        for (int off = 32; off > 0; off >>= 1) {
            s  += __shfl_down(s, off);
            ss += __shfl_down(ss, off);
        }
        if (lane == 0) { red[j][0][wid] = s; red[j][1][wid] = ss; }
    }
    __syncthreads();
    if (threadIdx.x < CO_BLK) {
        int j = threadIdx.x;
        float S  = red[j][0][0] + red[j][0][1];
        float SS = red[j][1][0] + red[j][1][1];
        atomicAdd(&sums[co0 + j], (double)S);
        atomicAdd(&sums[C_ + co0 + j], (double)SS);
    }
}

// Per-channel scale/shift from batch stats.
__global__ void finalize_kernel(const double* __restrict__ sums,
                                const float* __restrict__ gamma,
                                const float* __restrict__ beta,
                                float* __restrict__ sc)
{
    const int c = threadIdx.x;  // 64 threads
    const double cnt = (double)(N_ * HW_);
    double mean = sums[c] / cnt;
    double var  = sums[C_ + c] / cnt - mean * mean;
    float inv   = (float)(1.0 / sqrt(var + (double)BN_EPS));
    float scale = gamma[c] * inv;
    float shift = beta[c] - (float)mean * scale;
    sc[c]      = scale;
    sc[C_ + c] = shift;
}

// In-place BN affine + power activation, float4 vectorized.
// alpha==1 fast path: sign(t)*(|t|+1e-12)^1 = t +- 1e-12 (below tolerance).
__global__ __launch_bounds__(256) void apply_kernel(
    float* __restrict__ y, const float* __restrict__ sc,
    const float* __restrict__ alpha_p)
{
    const int idx = blockIdx.x * 256 + threadIdx.x;   // float4 index
    const float alpha = alpha_p[0];
    const int e0 = idx * 4;
    const int c = (e0 / HW_) & (C_ - 1);   // HW_ divisible by 4: all 4 in same channel
    const float scale = sc[c];
    const float shift = sc[C_ + c];

    float4 v = reinterpret_cast<float4*>(y)[idx];
    float* pv = reinterpret_cast<float*>(&v);
    if (alpha == 1.0f) {
#pragma unroll
        for (int i = 0; i < 4; ++i)
            pv[i] = pv[i] * scale + shift;
    } else {
#pragma unroll
        for (int i = 0; i < 4; ++i) {
            float t = pv[i] * scale + shift;
            float sgn = (t > 0.f) ? 1.f : ((t < 0.f) ? -1.f : 0.f);
            pv[i] = sgn * powf(fabsf(t) + POW_EPS, alpha);
        }
    }
    reinterpret_cast<float4*>(y)[idx] = v;
}

extern "C" void kernel_launch(void* const* d_in, const int* in_sizes, int n_in,
                              void* d_out, int out_size, void* d_ws, size_t ws_size,
                              hipStream_t stream)
{
    const float* x      = (const float*)d_in[0];
    const float* weight = (const float*)d_in[1];
    const float* gamma  = (const float*)d_in[2];
    const float* beta   = (const float*)d_in[3];
    const float* alpha  = (const float*)d_in[4];
    float* out = (float*)d_out;

    double* sums = (double*)d_ws;                                // 128 doubles
    float*  sc   = (float*)((char*)d_ws + 128 * sizeof(double)); // 128 floats

    hipMemsetAsync(d_ws, 0, 128 * sizeof(double), stream);

    adder_kernel<<<dim3(32, N_, N_CG), 128, 0, stream>>>(x, weight, out, sums);
    finalize_kernel<<<1, C_, 0, stream>>>(sums, gamma, beta, sc);

    const int n4 = (N_ * CHW_) / 4;           // 2,097,152 float4s
    apply_kernel<<<n4 / 256, 256, 0, stream>>>(out, sc, alpha);
}

// Round 12
// 293.246 us; speedup vs baseline: 1.4145x; 1.0278x over previous
//
#include <hip/hip_runtime.h>
#include <math.h>

#define N_   8
#define C_   64
#define H_   128
#define W_   128
#define HW_  (H_ * W_)
#define CHW_ (C_ * HW_)
#define K_   3
#define CI_TILE 4
#define CO_BLK  8
#define N_CG    (C_ / CO_BLK)   // 8 co-groups
#define TILE_H 16               // 8 row-threads x 2 px
#define TILE_W 32               // 16 col-threads x 2 px
#define HALO_H (TILE_H + 2)      // 18
#define HALO_W (TILE_W + 2)      // 34
#define XSTR   36                // b64-aligned row stride
#define CISZ   (HALO_H * XSTR)   // 648 floats per ci plane
#define PLANE  (HALO_H * HALO_W) // 612 staged elems per ci plane
#define NSLOT  5                 // ceil(612/128); slots 0..3 always in-range
#define WROW 12                  // padded weight row (9 used) -> 16B-aligned
#define WCI  (CO_BLK * WROW)     // 96 floats per ci
#define WSTRIDE (C_ * K_ * K_)   // 576 floats between consecutive co's
#define BN_EPS 1e-5
#define POW_EPS 1e-12f

// One |x-w| accumulate in EXACTLY 2 VALU instructions (VGPR operands).
#define MAC_TERM(accv, wv, xvk) do { float t_;                         \
    asm("v_sub_f32 %1, %2, %3\n\t"                                     \
        "v_add_f32 %0, %0, |%1|"                                       \
        : "+v"(accv), "=&v"(t_)                                        \
        : "v"(wv), "v"(xvk));                                          \
  } while (0)

// R11 post-mortem: VALU instr count is ~1.03x the 123us floor, yet wall is
// 2.07x -> SIMD slots ~50% empty with 3.5 waves/SIMD. All blocks are
// phase-locked (identical cadence), so co-resident blocks hit their
// stage->barrier window together (~800-1000 cyc of exposed global-load
// latency every ~2.7K cyc). Fix = async-STAGE split (T14): issue chunk k+1's
// global loads into REGISTERS before chunk k's MAC; after the barrier only
// ds_write the already-arrived values. Latency hides under the 2300-cyc MAC.
__global__ __launch_bounds__(128, 4) void adder_kernel(
    const float* __restrict__ x, const float* __restrict__ weight,
    float* __restrict__ y, double* __restrict__ sums)
{
    __shared__ __align__(16) float sx[CI_TILE * CISZ];   // 10368 B
    __shared__ __align__(16) float wl[CI_TILE * WCI];    //  1536 B
    __shared__ float red[CO_BLK][2][2];                  // stat partials

    const int tx = threadIdx.x & 15;        // col-pair 0..15
    const int ty = threadIdx.x >> 4;        // row-pair 0..7
    const int tile_h = blockIdx.x >> 2;     // 8 tiles of 16 rows
    const int tile_w = blockIdx.x & 3;      // 4 tiles of 32 cols
    const int n   = blockIdx.y;
    const int co0 = blockIdx.z * CO_BLK;
    const int h0 = tile_h * TILE_H;
    const int w0 = tile_w * TILE_W;

    float a00[CO_BLK], a01[CO_BLK], a10[CO_BLK], a11[CO_BLK];
#pragma unroll
    for (int j = 0; j < CO_BLK; ++j) { a00[j]=0.f; a01[j]=0.f; a10[j]=0.f; a11[j]=0.f; }

    const float* xn = x + n * CHW_;

    // One-time affine staging offsets (5 slots x 128 threads cover 612 elems).
    int lx[NSLOT], gx[NSLOT];
#pragma unroll
    for (int s = 0; s < NSLOT; ++s) {
        int idx = threadIdx.x + s * 128;
        if (idx < PLANE) {
            int r = idx / HALO_W, c = idx - r * HALO_W;
            int gh = h0 + r - 1, gw = w0 + c - 1;
            lx[s] = r * XSTR + c;
            gx[s] = ((unsigned)gh < (unsigned)H_ && (unsigned)gw < (unsigned)W_)
                    ? (gh * W_ + gw) : -1;
        } else { lx[s] = -1; gx[s] = -1; }
    }
    // weight slice: threads 0..71 each own one (co,k); ci loop affine.
    int wlo = -1, wgo = 0;
    if (threadIdx.x < CO_BLK * 9) {
        int co = threadIdx.x / 9, k = threadIdx.x - co * 9;
        wlo = co * WROW + k;
        wgo = (co0 + co) * WSTRIDE + k;
    }

    // Register staging buffers (all statically indexed -> stay in VGPRs).
    float rs[CI_TILE * NSLOT];
    float rw[CI_TILE];

    // Issue loads for chunk 0.
#define ISSUE_STAGE(CBN) do {                                            \
        const float* xp_ = xn + (CBN) * HW_;                             \
        _Pragma("unroll")                                                \
        for (int ci_ = 0; ci_ < CI_TILE; ++ci_) {                        \
            _Pragma("unroll")                                            \
            for (int s_ = 0; s_ < NSLOT; ++s_)                           \
                rs[ci_ * NSLOT + s_] = (gx[s_] >= 0)                     \
                    ? xp_[ci_ * HW_ + gx[s_]] : 0.f;                     \
        }                                                                \
        if (wlo >= 0) {                                                  \
            _Pragma("unroll")                                            \
            for (int ci_ = 0; ci_ < CI_TILE; ++ci_)                      \
                rw[ci_] = weight[wgo + ((CBN) + ci_) * 9];               \
        }                                                                \
    } while (0)

    ISSUE_STAGE(0);

    for (int cb = 0; cb < C_; cb += CI_TILE) {
        __syncthreads();  // previous chunk's LDS reads complete
        // Write already-arrived staged values to LDS (vmcnt wait here is
        // satisfied: loads were issued one full MAC phase ago).
#pragma unroll
        for (int ci = 0; ci < CI_TILE; ++ci) {
#pragma unroll
            for (int s = 0; s < NSLOT; ++s)
                if (lx[s] >= 0)
                    sx[ci * CISZ + lx[s]] = rs[ci * NSLOT + s];
        }
        if (wlo >= 0) {
#pragma unroll
            for (int ci = 0; ci < CI_TILE; ++ci)
                wl[ci * WCI + wlo] = rw[ci];
        }
        // Issue next chunk's loads; they fly under the MAC burst below.
        if (cb + CI_TILE < C_) ISSUE_STAGE(cb + CI_TILE);
        __syncthreads();  // sx/wl ready

#pragma unroll 1
        for (int ci = 0; ci < CI_TILE; ++ci) {
            const float* sxc = &sx[ci * CISZ];
            // 4x4 window serves the 2x2 pixel quad: 8x ds_read_b64.
            float xv[4][4];
#pragma unroll
            for (int r = 0; r < 4; ++r) {
                float2 a = *(const float2*)(sxc + (2 * ty + r) * XSTR + 2 * tx);
                float2 b = *(const float2*)(sxc + (2 * ty + r) * XSTR + 2 * tx + 2);
                xv[r][0] = a.x; xv[r][1] = a.y; xv[r][2] = b.x; xv[r][3] = b.y;
            }

            const float* wrow = &wl[ci * WCI];
#pragma unroll
            for (int j = 0; j < CO_BLK; ++j) {
                float4 wa = *(const float4*)(wrow + j * WROW);
                float4 wb = *(const float4*)(wrow + j * WROW + 4);
                float  w8 = wrow[j * WROW + 8];
                // tap (kh,kw) feeds pixel (pr,pc) from xv[pr+kh][pc+kw]
                MAC_TERM(a00[j], wa.x, xv[0][0]); MAC_TERM(a01[j], wa.x, xv[0][1]);
                MAC_TERM(a10[j], wa.x, xv[1][0]); MAC_TERM(a11[j], wa.x, xv[1][1]);
                MAC_TERM(a00[j], wa.y, xv[0][1]); MAC_TERM(a01[j], wa.y, xv[0][2]);
                MAC_TERM(a10[j], wa.y, xv[1][1]); MAC_TERM(a11[j], wa.y, xv[1][2]);
                MAC_TERM(a00[j], wa.z, xv[0][2]); MAC_TERM(a01[j], wa.z, xv[0][3]);
                MAC_TERM(a10[j], wa.z, xv[1][2]); MAC_TERM(a11[j], wa.z, xv[1][3]);
                MAC_TERM(a00[j], wa.w, xv[1][0]); MAC_TERM(a01[j], wa.w, xv[1][1]);
                MAC_TERM(a10[j], wa.w, xv[2][0]); MAC_TERM(a11[j], wa.w, xv[2][1]);
                MAC_TERM(a00[j], wb.x, xv[1][1]); MAC_TERM(a01[j], wb.x, xv[1][2]);
                MAC_TERM(a10[j], wb.x, xv[2][1]); MAC_TERM(a11[j], wb.x, xv[2][2]);
                MAC_TERM(a00[j], wb.y, xv[1][2]); MAC_TERM(a01[j], wb.y, xv[1][3]);
                MAC_TERM(a10[j], wb.y, xv[2][2]); MAC_TERM(a11[j], wb.y, xv[2][3]);
                MAC_TERM(a00[j], wb.z, xv[2][0]); MAC_TERM(a01[j], wb.z, xv[2][1]);
                MAC_TERM(a10[j], wb.z, xv[3][0]); MAC_TERM(a11[j], wb.z, xv[3][1]);
                MAC_TERM(a00[j], wb.w, xv[2][1]); MAC_TERM(a01[j], wb.w, xv[2][2]);
                MAC_TERM(a10[j], wb.w, xv[3][1]); MAC_TERM(a11[j], wb.w, xv[3][2]);
                MAC_TERM(a00[j], w8,   xv[2][2]); MAC_TERM(a01[j], w8,   xv[2][3]);
                MAC_TERM(a10[j], w8,   xv[3][2]); MAC_TERM(a11[j], w8,   xv[3][3]);
            }
        }
    }

    // Epilogue: y = -acc + residual (2 rows x float2); fused sum/sumsq.
    const int r0 = h0 + 2 * ty, c0 = w0 + 2 * tx;
    float* yo = y + n * CHW_ + co0 * HW_ + r0 * W_ + c0;
    const float* xrp = xn + co0 * HW_ + r0 * W_ + c0;
    const int lane = threadIdx.x & 63;
    const int wid  = threadIdx.x >> 6;   // 0..1 (2 waves)

#pragma unroll
    for (int j = 0; j < CO_BLK; ++j) {
        float2 rv0 = *(const float2*)(xrp + j * HW_);
        float2 rv1 = *(const float2*)(xrp + j * HW_ + W_);
        float v00 = -a00[j] + rv0.x, v01 = -a01[j] + rv0.y;
        float v10 = -a10[j] + rv1.x, v11 = -a11[j] + rv1.y;
        float2 o0; o0.x = v00; o0.y = v01;
        float2 o1; o1.x = v10; o1.y = v11;
        *(float2*)(yo + j * HW_)      = o0;
        *(float2*)(yo + j * HW_ + W_) = o1;
        float s  = v00 + v01 + v10 + v11;
        float ss = v00 * v00 + v01 * v01 + v10 * v10 + v11 * v11;
#pragma unroll
        for (int off = 32; off > 0; off >>= 1) {
            s  += __shfl_down(s, off);
            ss += __shfl_down(ss, off);
        }
        if (lane == 0) { red[j][0][wid] = s; red[j][1][wid] = ss; }
    }
    __syncthreads();
    if (threadIdx.x < CO_BLK) {
        int j = threadIdx.x;
        float S  = red[j][0][0] + red[j][0][1];
        float SS = red[j][1][0] + red[j][1][1];
        atomicAdd(&sums[co0 + j], (double)S);
        atomicAdd(&sums[C_ + co0 + j], (double)SS);
    }
}

// Per-channel scale/shift from batch stats.
__global__ void finalize_kernel(const double* __restrict__ sums,
                                const float* __restrict__ gamma,
                                const float* __restrict__ beta,
                                float* __restrict__ sc)
{
    const int c = threadIdx.x;  // 64 threads
    const double cnt = (double)(N_ * HW_);
    double mean = sums[c] / cnt;
    double var  = sums[C_ + c] / cnt - mean * mean;
    float inv   = (float)(1.0 / sqrt(var + (double)BN_EPS));
    float scale = gamma[c] * inv;
    float shift = beta[c] - (float)mean * scale;
    sc[c]      = scale;
    sc[C_ + c] = shift;
}

// In-place BN affine + power activation, float4 vectorized.
// alpha==1 fast path: sign(t)*(|t|+1e-12)^1 = t +- 1e-12 (below tolerance).
__global__ __launch_bounds__(256) void apply_kernel(
    float* __restrict__ y, const float* __restrict__ sc,
    const float* __restrict__ alpha_p)
{
    const int idx = blockIdx.x * 256 + threadIdx.x;   // float4 index
    const float alpha = alpha_p[0];
    const int e0 = idx * 4;
    const int c = (e0 / HW_) & (C_ - 1);   // HW_ divisible by 4: all 4 in same channel
    const float scale = sc[c];
    const float shift = sc[C_ + c];

    float4 v = reinterpret_cast<float4*>(y)[idx];
    float* pv = reinterpret_cast<float*>(&v);
    if (alpha == 1.0f) {
#pragma unroll
        for (int i = 0; i < 4; ++i)
            pv[i] = pv[i] * scale + shift;
    } else {
#pragma unroll
        for (int i = 0; i < 4; ++i) {
            float t = pv[i] * scale + shift;
            float sgn = (t > 0.f) ? 1.f : ((t < 0.f) ? -1.f : 0.f);
            pv[i] = sgn * powf(fabsf(t) + POW_EPS, alpha);
        }
    }
    reinterpret_cast<float4*>(y)[idx] = v;
}

extern "C" void kernel_launch(void* const* d_in, const int* in_sizes, int n_in,
                              void* d_out, int out_size, void* d_ws, size_t ws_size,
                              hipStream_t stream)
{
    const float* x      = (const float*)d_in[0];
    const float* weight = (const float*)d_in[1];
    const float* gamma  = (const float*)d_in[2];
    const float* beta   = (const float*)d_in[3];
    const float* alpha  = (const float*)d_in[4];
    float* out = (float*)d_out;

    double* sums = (double*)d_ws;                                // 128 doubles
    float*  sc   = (float*)((char*)d_ws + 128 * sizeof(double)); // 128 floats

    hipMemsetAsync(d_ws, 0, 128 * sizeof(double), stream);

    adder_kernel<<<dim3(32, N_, N_CG), 128, 0, stream>>>(x, weight, out, sums);
    finalize_kernel<<<1, C_, 0, stream>>>(sums, gamma, beta, sc);

    const int n4 = (N_ * CHW_) / 4;           // 2,097,152 float4s
    apply_kernel<<<n4 / 256, 256, 0, stream>>>(out, sc, alpha);
}